// Round 1
// baseline (239.541 us; speedup 1.0000x reference)
//
#include <hip/hip_runtime.h>

// out[b,e,t] = v2[t]*x[b,e,t] + sum_{s<t} v[s]*x[b,e,s]*d^(t-s) + bias[t]
// => decayed prefix scan along last axis. One 256-thread block per row,
// 8 elements per thread, shfl pair-scan + 4-wave LDS combine.

#define SEQ 2048
#define THREADS 256
#define PER_THREAD 8

__global__ __launch_bounds__(THREADS) void decay_scan_kernel(
    const float* __restrict__ x,
    const float* __restrict__ weight,
    const float* __restrict__ diag_weight,
    const float* __restrict__ bias,
    const float* __restrict__ decay,
    float* __restrict__ out)
{
    const int row  = blockIdx.x;
    const long base = (long)row * SEQ;
    const int tid  = threadIdx.x;
    const int lane = tid & 63;
    const int wv   = tid >> 6;

    // d = clip(decay_value[1,0], 0.9, 1.0)
    float d = decay[1];
    d = fminf(fmaxf(d, 0.9f), 1.0f);
    const float d2 = d * d, d4 = d2 * d2, d8 = d4 * d4;

    const int off = tid * PER_THREAD;

    const float4 x0 = *(const float4*)(x + base + off);
    const float4 x1 = *(const float4*)(x + base + off + 4);
    const float4 v0 = *(const float4*)(weight + off);
    const float4 v1 = *(const float4*)(weight + off + 4);

    float xs[PER_THREAD] = {x0.x, x0.y, x0.z, x0.w, x1.x, x1.y, x1.z, x1.w};
    float vs[PER_THREAD] = {v0.x, v0.y, v0.z, v0.w, v1.x, v1.y, v1.z, v1.w};

    // Local decayed scan: lp[k] = sum_{s<k in chunk} y[s] d^{k-s};
    // after loop c = sum_k y[k] d^{8-k} (chunk aggregate, decayed to boundary).
    float lp[PER_THREAD];
    float c = 0.f;
    #pragma unroll
    for (int k = 0; k < PER_THREAD; ++k) {
        lp[k] = c;
        c = d * (c + xs[k] * vs[k]);
    }

    // Wave-level inclusive pair-scan with operator:
    // combine(earlier=(s2,p2), mine=(s,p)) -> (s2*p + s, p2*p)
    float s = c, p = d8;
    #pragma unroll
    for (int o = 1; o < 64; o <<= 1) {
        float s2 = __shfl_up(s, o, 64);
        float p2 = __shfl_up(p, o, 64);
        if (lane >= o) { s = fmaf(s2, p, s); p = p2 * p; }
    }
    // exclusive within wave
    float es = __shfl_up(s, 1, 64);
    float ep = __shfl_up(p, 1, 64);
    if (lane == 0) { es = 0.f; ep = 1.f; }

    // cross-wave combine (4 waves)
    __shared__ float ws[4], wp[4];
    if (lane == 63) { ws[wv] = s; wp[wv] = p; }
    __syncthreads();
    float cs = 0.f;
    #pragma unroll
    for (int w = 0; w < 3; ++w) {
        if (w < wv) cs = fmaf(cs, wp[w], ws[w]);
    }
    // full exclusive prefix at this thread's chunk start: P[8*tid]
    const float C = fmaf(cs, ep, es);

    const float4 w0 = *(const float4*)(diag_weight + off);
    const float4 w1 = *(const float4*)(diag_weight + off + 4);
    const float4 b0 = *(const float4*)(bias + off);
    const float4 b1 = *(const float4*)(bias + off + 4);
    float v2s[PER_THREAD] = {w0.x, w0.y, w0.z, w0.w, w1.x, w1.y, w1.z, w1.w};
    float bs[PER_THREAD]  = {b0.x, b0.y, b0.z, b0.w, b1.x, b1.y, b1.z, b1.w};

    float res[PER_THREAD];
    float dk = 1.f;
    #pragma unroll
    for (int k = 0; k < PER_THREAD; ++k) {
        res[k] = fmaf(xs[k], v2s[k], fmaf(C, dk, lp[k]) + bs[k]);
        dk *= d;
    }

    float4 r0 = make_float4(res[0], res[1], res[2], res[3]);
    float4 r1 = make_float4(res[4], res[5], res[6], res[7]);
    *(float4*)(out + base + off)     = r0;
    *(float4*)(out + base + off + 4) = r1;
}

extern "C" void kernel_launch(void* const* d_in, const int* in_sizes, int n_in,
                              void* d_out, int out_size, void* d_ws, size_t ws_size,
                              hipStream_t stream) {
    const float* x           = (const float*)d_in[0];
    const float* weight      = (const float*)d_in[1];
    const float* diag_weight = (const float*)d_in[2];
    const float* bias        = (const float*)d_in[3];
    const float* decay       = (const float*)d_in[4];
    float* out = (float*)d_out;

    const int rows = in_sizes[0] / SEQ;  // B*E = 16384
    decay_scan_kernel<<<rows, THREADS, 0, stream>>>(
        x, weight, diag_weight, bias, decay, out);
}